// Round 2
// baseline (433.384 us; speedup 1.0000x reference)
//
#include <hip/hip_runtime.h>
#include <hip/hip_bf16.h>

#define EMB 300
#define HID 10
#define BATCH 256
#define SEQ 512
#define ROWS (BATCH * SEQ)   // 131072
#define G3 (3 * HID)         // 30

#define TPB_GI 128
#define RPT 4                // rows per thread in k_gi

// fast sigmoid / tanh via hardware exp2/rcp (plenty of precision for 2.75e-2 abs threshold)
__device__ __forceinline__ float fsig(float x) {
    float e = __builtin_amdgcn_exp2f(-1.4426950408889634f * x);
    return __builtin_amdgcn_rcpf(1.0f + e);
}
__device__ __forceinline__ float ftanh(float x) {
    float e = __builtin_amdgcn_exp2f(2.8853900817779268f * x);
    return fmaf(-2.0f, __builtin_amdgcn_rcpf(1.0f + e), 1.0f);
}
__device__ __forceinline__ float rdlane(float v, int lane) {
    return __int_as_float(__builtin_amdgcn_readlane(__float_as_int(v), lane));
}

// ---------------------------------------------------------------------------
// Kernel 1: gi[g][row] = b_ih[g] + sum_e x[row][e] * w_ih[g][e]
// v2: 4 rows/thread -> each ds_read_b128 weight broadcast feeds 16 FMAs
// (v1 was LDS-instruction-bound: 30 broadcasts per 120 FMAs).
// 128 thr x 256 blocks = 1 block/CU, rows strided by 128 within block.
// ---------------------------------------------------------------------------
__global__ __launch_bounds__(TPB_GI, 1) void k_gi(const float* __restrict__ x,
                                                  const float* __restrict__ w_ih,
                                                  const float* __restrict__ b_ih,
                                                  float* __restrict__ gi) {
    __shared__ float ws[G3 * EMB]; // 36 KB
    for (int i = threadIdx.x; i < (G3 * EMB) / 4; i += TPB_GI)
        ((float4*)ws)[i] = ((const float4*)w_ih)[i];
    __syncthreads();

    const int base = blockIdx.x * (TPB_GI * RPT) + threadIdx.x;
    const float* __restrict__ xr[RPT];
#pragma unroll
    for (int r = 0; r < RPT; r++) xr[r] = x + (size_t)(base + r * TPB_GI) * EMB;

    float acc[RPT][G3];
#pragma unroll
    for (int r = 0; r < RPT; r++)
#pragma unroll
        for (int g = 0; g < G3; g++) acc[r][g] = 0.0f;

#pragma unroll 1
    for (int k = 0; k < EMB; k += 4) {
        float4 xv[RPT];
#pragma unroll
        for (int r = 0; r < RPT; r++) xv[r] = *(const float4*)(xr[r] + k);
#pragma unroll
        for (int g = 0; g < G3; g++) {
            const float4 wv = *(const float4*)(&ws[g * EMB + k]);
#pragma unroll
            for (int r = 0; r < RPT; r++) {
                acc[r][g] = fmaf(xv[r].x, wv.x, acc[r][g]);
                acc[r][g] = fmaf(xv[r].y, wv.y, acc[r][g]);
                acc[r][g] = fmaf(xv[r].z, wv.z, acc[r][g]);
                acc[r][g] = fmaf(xv[r].w, wv.w, acc[r][g]);
            }
        }
    }
#pragma unroll
    for (int g = 0; g < G3; g++) {
        const float bg = b_ih[g];
#pragma unroll
        for (int r = 0; r < RPT; r++)
            gi[(size_t)g * ROWS + base + r * TPB_GI] = acc[r][g] + bg;
    }
}

// ---------------------------------------------------------------------------
// Kernel 2: backward direction = ONE GRU step on x[:, SEQ-1] with h0 = 0.
// ---------------------------------------------------------------------------
__global__ __launch_bounds__(64) void k_back(const float* __restrict__ x,
                                             const float* __restrict__ w_ih_b,
                                             const float* __restrict__ b_ih_b,
                                             const float* __restrict__ b_hh_b,
                                             float* __restrict__ hb) {
    const int b = blockIdx.x;
    const int j = threadIdx.x;
    const int gc = j < G3 ? j : G3 - 1;

    const float* __restrict__ xr = x + ((size_t)b * SEQ + (SEQ - 1)) * EMB;
    const float* __restrict__ wr = w_ih_b + (size_t)gc * EMB;

    float acc = b_ih_b[gc];
    for (int k = 0; k < EMB; k += 4) {
        const float4 xv = *(const float4*)(xr + k);
        const float4 wv = *(const float4*)(wr + k);
        acc = fmaf(xv.x, wv.x, acc);
        acc = fmaf(xv.y, wv.y, acc);
        acc = fmaf(xv.z, wv.z, acc);
        acc = fmaf(xv.w, wv.w, acc);
    }
    const int jc = j < HID ? j : 0;
    const float i_r = acc;
    const float i_z = __shfl(acc, jc + HID, 64);
    const float i_n = __shfl(acc, jc + 2 * HID, 64);
    const float r = fsig(i_r + b_hh_b[jc]);
    const float z = fsig(i_z + b_hh_b[HID + jc]);
    const float n = ftanh(fmaf(r, b_hh_b[2 * HID + jc], i_n));
    if (j < HID) hb[b * HID + j] = (1.0f - z) * n;
}

// ---------------------------------------------------------------------------
// Kernel 3: forward recurrence, one wave per batch element.
// v2: depth-4 rolling register prefetch of gi (12 loads in flight) to cover
// L2 latency; b_hh r/z biases folded into the prefetched values.
// ---------------------------------------------------------------------------
#define PFD 4
__global__ __launch_bounds__(64) void k_scan(const float* __restrict__ gi,
                                             const float* __restrict__ w_hh,
                                             const float* __restrict__ b_hh,
                                             const float* __restrict__ hb,
                                             const float* __restrict__ w_lin,
                                             const float* __restrict__ b_lin,
                                             float* __restrict__ out) {
    const int b = blockIdx.x;
    const int j = threadIdx.x;
    const int jc = j < HID ? j : HID - 1;

    float wr[HID], wz[HID], wn[HID];
#pragma unroll
    for (int k = 0; k < HID; k++) {
        wr[k] = w_hh[jc * HID + k];
        wz[k] = w_hh[(HID + jc) * HID + k];
        wn[k] = w_hh[(2 * HID + jc) * HID + k];
    }
    const float br = b_hh[jc];
    const float bz = b_hh[HID + jc];
    const float bn = b_hh[2 * HID + jc];

    const float* __restrict__ gr = gi + (size_t)jc * ROWS + (size_t)b * SEQ;
    const float* __restrict__ gz = gi + (size_t)(HID + jc) * ROWS + (size_t)b * SEQ;
    const float* __restrict__ gn = gi + (size_t)(2 * HID + jc) * ROWS + (size_t)b * SEQ;

    float h = 0.0f;
    float hs[HID];
#pragma unroll
    for (int k = 0; k < HID; k++) hs[k] = 0.0f;

    float pr[PFD], pz[PFD], pn[PFD];
#pragma unroll
    for (int d = 0; d < PFD; d++) {
        pr[d] = gr[d] + br;
        pz[d] = gz[d] + bz;
        pn[d] = gn[d];
    }

    for (int t = 0; t < SEQ; t += PFD) {
#pragma unroll
        for (int d = 0; d < PFD; d++) {
            const int tt = t + d;
            const float ir = pr[d];
            const float iz = pz[d];
            const float in_ = pn[d];

            int tn = tt + PFD;                 // refill this slot 4 steps ahead
            if (tn >= SEQ) tn = SEQ - 1;
            pr[d] = gr[tn] + br;
            pz[d] = gz[tn] + bz;
            pn[d] = gn[tn];

            float ar = ir;
            float az = iz;
            float an = bn;
#pragma unroll
            for (int k = 0; k < HID; k++) {
                ar = fmaf(wr[k], hs[k], ar);
                az = fmaf(wz[k], hs[k], az);
                an = fmaf(wn[k], hs[k], an);
            }
            const float r = fsig(ar);
            const float z = fsig(az);
            const float n = ftanh(fmaf(r, an, in_));
            h = fmaf(z, h - n, n);             // (1-z)*n + z*h

#pragma unroll
            for (int k = 0; k < HID; k++) hs[k] = rdlane(h, k);
        }
    }

    // fused Linear(2H -> 1)
    const float hbv = hb[b * HID + jc];
    const float p = fmaf(w_lin[jc], h, w_lin[HID + jc] * hbv);
    float s = 0.0f;
#pragma unroll
    for (int k = 0; k < HID; k++) s += rdlane(p, k);
    if (j == 0) out[b] = s + b_lin[0];
}

// ---------------------------------------------------------------------------
extern "C" void kernel_launch(void* const* d_in, const int* in_sizes, int n_in,
                              void* d_out, int out_size, void* d_ws, size_t ws_size,
                              hipStream_t stream) {
    const float* x      = (const float*)d_in[0];
    const float* w_ih_f = (const float*)d_in[1];
    const float* w_hh_f = (const float*)d_in[2];
    const float* b_ih_f = (const float*)d_in[3];
    const float* b_hh_f = (const float*)d_in[4];
    const float* w_ih_b = (const float*)d_in[5];
    const float* w_hh_b = (const float*)d_in[6];   // unused: backward is a single step, h0=0
    const float* b_ih_b = (const float*)d_in[7];
    const float* b_hh_b = (const float*)d_in[8];
    const float* w_lin  = (const float*)d_in[9];
    const float* b_lin  = (const float*)d_in[10];
    float* out = (float*)d_out;

    float* gi = (float*)d_ws;                       // [30][ROWS] = 15.73 MB
    float* hb = gi + (size_t)G3 * ROWS;             // [BATCH][HID]
    (void)w_hh_b; (void)in_sizes; (void)n_in; (void)out_size; (void)ws_size;

    k_gi  <<<ROWS / (TPB_GI * RPT), TPB_GI, 0, stream>>>(x, w_ih_f, b_ih_f, gi);
    k_back<<<BATCH, 64, 0, stream>>>(x, w_ih_b, b_ih_b, b_hh_b, hb);
    k_scan<<<BATCH, 64, 0, stream>>>(gi, w_hh_f, b_hh_f, hb, w_lin, b_lin, out);
}

// Round 3
// 357.408 us; speedup vs baseline: 1.2126x; 1.2126x over previous
//
#include <hip/hip_runtime.h>
#include <hip/hip_bf16.h>

#define EMB 300
#define HID 10
#define BATCH 256
#define SEQ 512
#define ROWS (BATCH * SEQ)    // 131072
#define G3 (3 * HID)          // 30
#define KT 10                 // k-tiles of 32 (tile 9 offset 268, masked weights)

typedef __attribute__((ext_vector_type(8))) short short8;   // 8 bf16 = 4 VGPRs
typedef __attribute__((ext_vector_type(4))) float f32x4;    // MFMA C/D

// fast sigmoid / tanh via hardware exp2/rcp
__device__ __forceinline__ float fsig(float x) {
    float e = __builtin_amdgcn_exp2f(-1.4426950408889634f * x);
    return __builtin_amdgcn_rcpf(1.0f + e);
}
__device__ __forceinline__ float ftanh(float x) {
    float e = __builtin_amdgcn_exp2f(2.8853900817779268f * x);
    return fmaf(-2.0f, __builtin_amdgcn_rcpf(1.0f + e), 1.0f);
}
__device__ __forceinline__ float rdlane(float v, int lane) {
    return __int_as_float(__builtin_amdgcn_readlane(__float_as_int(v), lane));
}
__device__ __forceinline__ short bf16_hi(float f) {          // truncation split: hi part
    return (short)(__float_as_uint(f) >> 16);
}
__device__ __forceinline__ float bf16_tof(short h) {
    return __uint_as_float(((unsigned)(unsigned short)h) << 16);
}

// ---------------------------------------------------------------------------
// Prep: padded, k-tiled, split-bf16 weights wp[32 gates][320 k].
// Tiles 0..8 cover k=0..287; tile 9 covers x-offset 268..299 but only
// i>=20 (k>=288) nonzero, so nothing is double-counted and x reads never
// cross a row boundary (no OOB on the last row).
// ---------------------------------------------------------------------------
__global__ void k_prep(const float* __restrict__ w_ih,
                       short* __restrict__ wph, short* __restrict__ wpl) {
    int i = blockIdx.x * 256 + threadIdx.x;
    if (i >= 32 * 320) return;
    int g = i / 320, kk = i % 320;
    int kt = kk >> 5, ki = kk & 31;
    int k = (kt < 9) ? kk : 268 + ki;                 // tile-9 x offset base 268
    bool live = (g < 30) && ((kt < 9) ? (k < 300) : (ki >= 20));
    float v = live ? w_ih[g * EMB + k] : 0.0f;
    short hi = bf16_hi(v);
    float lo = v - bf16_tof(hi);
    wph[i] = hi;
    wpl[i] = bf16_hi(lo);
}

// ---------------------------------------------------------------------------
// Kernel 1: gi[row][g] = b_ih[g] + x[row]·w_ih[g]  via split-bf16 MFMA.
// One 16-row tile per wave; A-fragments straight from global (no LDS).
// A layout: A[m=lane&15][k=quad*8+j]; B: B[k=quad*8+j][n=lane&15];
// C: col=lane&15, row=quad*4+reg.
// ---------------------------------------------------------------------------
__global__ __launch_bounds__(256) void k_gi(const float* __restrict__ x,
                                            const short* __restrict__ wph,
                                            const short* __restrict__ wpl,
                                            const float* __restrict__ b_ih,
                                            float* __restrict__ gi) {
    const int wid  = (blockIdx.x * 256 + threadIdx.x) >> 6;   // tile id, 0..8191
    const int lane = threadIdx.x & 63;
    const int m = lane & 15, q = lane >> 4;
    const int m0 = wid * 16;

    const float bias0 = b_ih[m];                               // m<16<30 always live
    const int   g1    = 16 + m;
    const float bias1 = (g1 < 30) ? b_ih[(g1 < 30) ? g1 : 29] : 0.0f;
    f32x4 acc0 = {bias0, bias0, bias0, bias0};
    f32x4 acc1 = {bias1, bias1, bias1, bias1};

    const size_t xrow  = (size_t)(m0 + m) * EMB;
    const int    wrow0 = m * 320;
    const int    wrow1 = (16 + m) * 320;

#pragma unroll
    for (int kt = 0; kt < KT; kt++) {
        const int k0 = (kt < 9) ? kt * 32 : 268;               // in-row, never OOB
        const size_t off = xrow + k0 + q * 8;
        const float4 xa = *(const float4*)(x + off);
        const float4 xb = *(const float4*)(x + off + 4);
        float av[8] = {xa.x, xa.y, xa.z, xa.w, xb.x, xb.y, xb.z, xb.w};

        short8 ah, al;
#pragma unroll
        for (int j = 0; j < 8; j++) {
            short hi = bf16_hi(av[j]);
            ah[j] = hi;
            al[j] = bf16_hi(av[j] - bf16_tof(hi));
        }
        const int wo = kt * 32 + q * 8;
        short8 bh0 = *(const short8*)(wph + wrow0 + wo);
        short8 bl0 = *(const short8*)(wpl + wrow0 + wo);
        short8 bh1 = *(const short8*)(wph + wrow1 + wo);
        short8 bl1 = *(const short8*)(wpl + wrow1 + wo);

        acc0 = __builtin_amdgcn_mfma_f32_16x16x32_bf16(ah, bh0, acc0, 0, 0, 0);
        acc0 = __builtin_amdgcn_mfma_f32_16x16x32_bf16(al, bh0, acc0, 0, 0, 0);
        acc0 = __builtin_amdgcn_mfma_f32_16x16x32_bf16(ah, bl0, acc0, 0, 0, 0);
        acc1 = __builtin_amdgcn_mfma_f32_16x16x32_bf16(ah, bh1, acc1, 0, 0, 0);
        acc1 = __builtin_amdgcn_mfma_f32_16x16x32_bf16(al, bh1, acc1, 0, 0, 0);
        acc1 = __builtin_amdgcn_mfma_f32_16x16x32_bf16(ah, bl1, acc1, 0, 0, 0);
    }
#pragma unroll
    for (int r = 0; r < 4; r++) {
        const size_t row = (size_t)(m0 + q * 4 + r);
        gi[row * 32 + m]      = acc0[r];
        gi[row * 32 + 16 + m] = acc1[r];
    }
}

// ---------------------------------------------------------------------------
// Kernel 2: backward direction = ONE GRU step on x[:, SEQ-1], h0 = 0.
// x row staged in LDS (broadcast reads); lanes 0..29 = gate dots.
// ---------------------------------------------------------------------------
__global__ __launch_bounds__(128) void k_back(const float* __restrict__ x,
                                              const float* __restrict__ w_ih_b,
                                              const float* __restrict__ b_ih_b,
                                              const float* __restrict__ b_hh_b,
                                              float* __restrict__ hb) {
    __shared__ float xs[EMB];
    const int b = blockIdx.x;
    const int t = threadIdx.x;
    const float* __restrict__ xr = x + ((size_t)b * SEQ + (SEQ - 1)) * EMB;
    if (t < EMB / 4) ((float4*)xs)[t] = ((const float4*)xr)[t];
    __syncthreads();
    if (t >= 64) return;

    const int g = (t < G3) ? t : G3 - 1;
    const float* __restrict__ wr = w_ih_b + (size_t)g * EMB;
    float acc = b_ih_b[g];
    for (int k = 0; k < EMB; k += 4) {
        const float4 wv = *(const float4*)(wr + k);
        acc = fmaf(xs[k],     wv.x, acc);
        acc = fmaf(xs[k + 1], wv.y, acc);
        acc = fmaf(xs[k + 2], wv.z, acc);
        acc = fmaf(xs[k + 3], wv.w, acc);
    }
    const int jc = (t < HID) ? t : 0;
    const float i_r = acc;
    const float i_z = __shfl(acc, jc + HID, 64);
    const float i_n = __shfl(acc, jc + 2 * HID, 64);
    const float r = fsig(i_r + b_hh_b[jc]);
    const float z = fsig(i_z + b_hh_b[HID + jc]);
    const float n = ftanh(fmaf(r, b_hh_b[2 * HID + jc], i_n));
    if (t < HID) hb[b * HID + t] = (1.0f - z) * n;
}

// ---------------------------------------------------------------------------
// Kernel 3: forward recurrence, one wave per batch. gi is row-major [row][32]
// so the 3 per-step loads hit ONE 128-B line; ring prefetch depth 8 (24 loads
// in flight, ~800+ cyc lookahead > L3 latency). Fused final Linear.
// ---------------------------------------------------------------------------
#define PFD 8
__global__ __launch_bounds__(64) void k_scan(const float* __restrict__ gi,
                                             const float* __restrict__ w_hh,
                                             const float* __restrict__ b_hh,
                                             const float* __restrict__ hb,
                                             const float* __restrict__ w_lin,
                                             const float* __restrict__ b_lin,
                                             float* __restrict__ out) {
    const int b = blockIdx.x;
    const int j = threadIdx.x;
    const int jc = (j < HID) ? j : HID - 1;

    float wr[HID], wz[HID], wn[HID];
#pragma unroll
    for (int k = 0; k < HID; k++) {
        wr[k] = w_hh[jc * HID + k];
        wz[k] = w_hh[(HID + jc) * HID + k];
        wn[k] = w_hh[(2 * HID + jc) * HID + k];
    }
    const float br = b_hh[jc];
    const float bz = b_hh[HID + jc];
    const float bn = b_hh[2 * HID + jc];

    const float* __restrict__ gb = gi + (size_t)b * SEQ * 32;

    float pr[PFD], pz[PFD], pn[PFD];
#pragma unroll
    for (int d = 0; d < PFD; d++) {
        pr[d] = gb[d * 32 + jc];
        pz[d] = gb[d * 32 + HID + jc];
        pn[d] = gb[d * 32 + 2 * HID + jc];
    }

    float h = 0.0f;
    float hs[HID];
#pragma unroll
    for (int k = 0; k < HID; k++) hs[k] = 0.0f;

    for (int t = 0; t < SEQ; t += PFD) {
#pragma unroll
        for (int d = 0; d < PFD; d++) {
            const float ir = pr[d], iz = pz[d], in_ = pn[d];

            int tn = t + d + PFD;                  // refill PFD steps ahead
            if (tn >= SEQ) tn = SEQ - 1;
            const float* __restrict__ gp = gb + (size_t)tn * 32;
            pr[d] = gp[jc];
            pz[d] = gp[HID + jc];
            pn[d] = gp[2 * HID + jc];

            float ar = ir + br;
            float az = iz + bz;
            float an = bn;
#pragma unroll
            for (int k = 0; k < HID; k++) {
                ar = fmaf(wr[k], hs[k], ar);
                az = fmaf(wz[k], hs[k], az);
                an = fmaf(wn[k], hs[k], an);
            }
            const float r = fsig(ar);
            const float z = fsig(az);
            const float n = ftanh(fmaf(r, an, in_));
            h = fmaf(z, h - n, n);                 // (1-z)*n + z*h

#pragma unroll
            for (int k = 0; k < HID; k++) hs[k] = rdlane(h, k);
        }
    }

    const float hbv = hb[b * HID + jc];
    const float p = fmaf(w_lin[jc], h, w_lin[HID + jc] * hbv);
    float s = 0.0f;
#pragma unroll
    for (int k = 0; k < HID; k++) s += rdlane(p, k);
    if (j == 0) out[b] = s + b_lin[0];
}

// ---------------------------------------------------------------------------
extern "C" void kernel_launch(void* const* d_in, const int* in_sizes, int n_in,
                              void* d_out, int out_size, void* d_ws, size_t ws_size,
                              hipStream_t stream) {
    const float* x      = (const float*)d_in[0];
    const float* w_ih_f = (const float*)d_in[1];
    const float* w_hh_f = (const float*)d_in[2];
    const float* b_ih_f = (const float*)d_in[3];
    const float* b_hh_f = (const float*)d_in[4];
    const float* w_ih_b = (const float*)d_in[5];
    const float* w_hh_b = (const float*)d_in[6];   // unused: backward is one step, h0=0
    const float* b_ih_b = (const float*)d_in[7];
    const float* b_hh_b = (const float*)d_in[8];
    const float* w_lin  = (const float*)d_in[9];
    const float* b_lin  = (const float*)d_in[10];
    float* out = (float*)d_out;

    float* gi  = (float*)d_ws;                          // [ROWS][32] = 16.78 MB
    float* hb  = gi + (size_t)ROWS * 32;                // [BATCH][HID]
    short* wph = (short*)(hb + BATCH * HID);            // [32][320] bf16-hi
    short* wpl = wph + 32 * 320;                        // [32][320] bf16-lo
    (void)w_hh_b; (void)in_sizes; (void)n_in; (void)out_size; (void)ws_size;

    k_prep<<<(32 * 320 + 255) / 256, 256, 0, stream>>>(w_ih_f, wph, wpl);
    k_back<<<BATCH, 128, 0, stream>>>(x, w_ih_b, b_ih_b, b_hh_b, hb);
    k_gi  <<<(ROWS / 16) / 4, 256, 0, stream>>>(x, wph, wpl, b_ih_f, gi);
    k_scan<<<BATCH, 64, 0, stream>>>(gi, w_hh_f, b_hh_f, hb, w_lin, b_lin, out);
}

// Round 4
// 330.148 us; speedup vs baseline: 1.3127x; 1.0826x over previous
//
#include <hip/hip_runtime.h>
#include <hip/hip_bf16.h>

#define EMB 300
#define HID 10
#define BATCH 256
#define SEQ 512
#define ROWS (BATCH * SEQ)    // 131072
#define G3 (3 * HID)          // 30
#define KT 10                 // k-tiles of 32 (tile 9 offset 268, masked weights)
#define XP 36                 // padded LDS row stride (floats): 16B-aligned, 2-way banks

typedef __attribute__((ext_vector_type(8))) short short8;   // 8 bf16 = 4 VGPRs
typedef __attribute__((ext_vector_type(4))) float f32x4;    // MFMA C/D

__device__ __forceinline__ float fsig(float x) {
    float e = __builtin_amdgcn_exp2f(-1.4426950408889634f * x);
    return __builtin_amdgcn_rcpf(1.0f + e);
}
__device__ __forceinline__ float ftanh(float x) {
    float e = __builtin_amdgcn_exp2f(2.8853900817779268f * x);
    return fmaf(-2.0f, __builtin_amdgcn_rcpf(1.0f + e), 1.0f);
}
__device__ __forceinline__ float rdlane(float v, int lane) {
    return __int_as_float(__builtin_amdgcn_readlane(__float_as_int(v), lane));
}
__device__ __forceinline__ short bf16_hi(float f) {
    return (short)(__float_as_uint(f) >> 16);
}
__device__ __forceinline__ float bf16_tof(short h) {
    return __uint_as_float(((unsigned)(unsigned short)h) << 16);
}

// ---------------------------------------------------------------------------
// Prep: padded, k-tiled, split-bf16 weights wp[32 gates][320 k].
// Tiles 0..8 cover k=0..287; tile 9 covers x-offset 268..299, live only ki>=20
// (k>=288) so nothing is double-counted and x reads stay in-row.
// ---------------------------------------------------------------------------
__global__ void k_prep(const float* __restrict__ w_ih,
                       short* __restrict__ wph, short* __restrict__ wpl) {
    int i = blockIdx.x * 256 + threadIdx.x;
    if (i >= 32 * 320) return;
    int g = i / 320, kk = i % 320;
    int kt = kk >> 5, ki = kk & 31;
    int k = (kt < 9) ? kk : 268 + ki;
    bool live = (g < 30) && ((kt < 9) ? (k < 300) : (ki >= 20));
    float v = live ? w_ih[g * EMB + k] : 0.0f;
    short hi = bf16_hi(v);
    float lo = v - bf16_tof(hi);
    wph[i] = hi;
    wpl[i] = bf16_hi(lo);
}

// ---------------------------------------------------------------------------
// Kernel 1: gi[row][g] = b_ih[g] + x[row]·w_ih[g]  via split-bf16 MFMA.
// v4: block = 256 thr handles 64 rows; per k-tile the x chunk (64 rows x 32
// floats) is staged into LDS COALESCED (8 thr cover one row's 128 B dense),
// then A-fragments come from ds_read_b128. Fixes the 1200-B-stride lane
// divergence that made v3 VMEM-issue bound (93 us @ 4.7% VALUBusy).
// ---------------------------------------------------------------------------
__global__ __launch_bounds__(256) void k_gi(const float* __restrict__ x,
                                            const short* __restrict__ wph,
                                            const short* __restrict__ wpl,
                                            const float* __restrict__ b_ih,
                                            float* __restrict__ gi) {
    __shared__ float xs[64 * XP];                 // 9216 B
    const int t    = threadIdx.x;
    const int wave = t >> 6, lane = t & 63;
    const int m = lane & 15, q = lane >> 4;
    const int base = blockIdx.x * 64;             // first of 64 rows
    const int rloc = wave * 16 + m;               // this lane's fragment row

    const float bias0 = b_ih[m];
    const float bias1 = (16 + m < G3) ? b_ih[16 + m] : 0.0f;
    f32x4 acc0 = {bias0, bias0, bias0, bias0};
    f32x4 acc1 = {bias1, bias1, bias1, bias1};

    const int srow  = t >> 3;                     // staging: 8 thr per row
    const int spiece = (t & 7) * 4;
    const float* __restrict__ xg0 = x + (size_t)(base + srow) * EMB + spiece;
    const float* __restrict__ xg1 = x + (size_t)(base + 32 + srow) * EMB + spiece;
    float* __restrict__ xs0 = xs + srow * XP + spiece;
    float* __restrict__ xs1 = xs + (32 + srow) * XP + spiece;

    const int wrow0 = m * 320;
    const int wrow1 = (16 + m) * 320;

#pragma unroll
    for (int kt = 0; kt < KT; kt++) {
        const int k0 = (kt < 9) ? kt * 32 : 268;  // in-row, never OOB
        __syncthreads();                          // prev tile's reads done
        *(float4*)xs0 = *(const float4*)(xg0 + k0);
        *(float4*)xs1 = *(const float4*)(xg1 + k0);
        __syncthreads();

        const float* fp = xs + rloc * XP + q * 8;
        const float4 xa = *(const float4*)fp;
        const float4 xb = *(const float4*)(fp + 4);
        float av[8] = {xa.x, xa.y, xa.z, xa.w, xb.x, xb.y, xb.z, xb.w};

        short8 ah, al;
#pragma unroll
        for (int j = 0; j < 8; j++) {
            short hi = bf16_hi(av[j]);
            ah[j] = hi;
            al[j] = bf16_hi(av[j] - bf16_tof(hi));
        }
        const int wo = kt * 32 + q * 8;
        short8 bh0 = *(const short8*)(wph + wrow0 + wo);
        short8 bl0 = *(const short8*)(wpl + wrow0 + wo);
        short8 bh1 = *(const short8*)(wph + wrow1 + wo);
        short8 bl1 = *(const short8*)(wpl + wrow1 + wo);

        acc0 = __builtin_amdgcn_mfma_f32_16x16x32_bf16(ah, bh0, acc0, 0, 0, 0);
        acc0 = __builtin_amdgcn_mfma_f32_16x16x32_bf16(al, bh0, acc0, 0, 0, 0);
        acc0 = __builtin_amdgcn_mfma_f32_16x16x32_bf16(ah, bl0, acc0, 0, 0, 0);
        acc1 = __builtin_amdgcn_mfma_f32_16x16x32_bf16(ah, bh1, acc1, 0, 0, 0);
        acc1 = __builtin_amdgcn_mfma_f32_16x16x32_bf16(al, bh1, acc1, 0, 0, 0);
        acc1 = __builtin_amdgcn_mfma_f32_16x16x32_bf16(ah, bl1, acc1, 0, 0, 0);
    }
#pragma unroll
    for (int r = 0; r < 4; r++) {
        const size_t row = (size_t)(base + wave * 16 + q * 4 + r);
        gi[row * 32 + m]      = acc0[r];
        gi[row * 32 + 16 + m] = acc1[r];
    }
}

// ---------------------------------------------------------------------------
// Kernel 2: backward direction = ONE GRU step on x[:, SEQ-1], h0 = 0.
// v4: 30 gates x 8 threads, COALESCED 128-B weight reads, shfl group-reduce.
// ---------------------------------------------------------------------------
__global__ __launch_bounds__(256) void k_back(const float* __restrict__ x,
                                              const float* __restrict__ w_ih_b,
                                              const float* __restrict__ b_ih_b,
                                              const float* __restrict__ b_hh_b,
                                              float* __restrict__ hb) {
    __shared__ float xs[EMB];
    __shared__ float gsum[G3];
    const int b = blockIdx.x;
    const int t = threadIdx.x;
    const float* __restrict__ xr = x + ((size_t)b * SEQ + (SEQ - 1)) * EMB;
    if (t < EMB / 4) ((float4*)xs)[t] = ((const float4*)xr)[t];
    __syncthreads();

    if (t < G3 * 8) {
        const int g = t >> 3, j = t & 7;
        float acc = 0.0f;
#pragma unroll
        for (int i = 0; i < 10; i++) {
            const int k = j * 4 + i * 32;
            if (k < EMB) {
                const float4 wv = *(const float4*)(w_ih_b + (size_t)g * EMB + k);
                acc = fmaf(xs[k],     wv.x, acc);
                acc = fmaf(xs[k + 1], wv.y, acc);
                acc = fmaf(xs[k + 2], wv.z, acc);
                acc = fmaf(xs[k + 3], wv.w, acc);
            }
        }
        acc += __shfl_down(acc, 4, 8);
        acc += __shfl_down(acc, 2, 8);
        acc += __shfl_down(acc, 1, 8);
        if (j == 0) gsum[g] = acc + b_ih_b[g];
    }
    __syncthreads();
    if (t < HID) {
        const float r = fsig(gsum[t] + b_hh_b[t]);
        const float z = fsig(gsum[HID + t] + b_hh_b[HID + t]);
        const float n = ftanh(fmaf(r, b_hh_b[2 * HID + t], gsum[2 * HID + t]));
        hb[b * HID + t] = (1.0f - z) * n;
    }
}

// ---------------------------------------------------------------------------
// Kernel 3: forward recurrence. v4: stage the block's WHOLE gi slice (64 KB)
// into LDS coalesced with 256 threads, then the scan loop touches only LDS
// (deterministic ~120 cyc latency, depth-4 ring covers it). Dots use 2
// accumulators to halve the serial FMA chain. Fused final Linear.
// ---------------------------------------------------------------------------
#define PFD 4
__global__ __launch_bounds__(256) void k_scan(const float* __restrict__ gi,
                                              const float* __restrict__ w_hh,
                                              const float* __restrict__ b_hh,
                                              const float* __restrict__ hb,
                                              const float* __restrict__ w_lin,
                                              const float* __restrict__ b_lin,
                                              float* __restrict__ out) {
    __shared__ float gs[SEQ * 32];                      // 64 KB
    const int b = blockIdx.x;
    const int t = threadIdx.x;

    const float4* __restrict__ src = (const float4*)(gi + (size_t)b * SEQ * 32);
#pragma unroll
    for (int i = 0; i < (SEQ * 32 / 4) / 256; i++)
        ((float4*)gs)[i * 256 + t] = src[i * 256 + t];
    __syncthreads();
    if (t >= 64) return;

    const int j = t;
    const int jc = (j < HID) ? j : HID - 1;

    float wr[HID], wz[HID], wn[HID];
#pragma unroll
    for (int k = 0; k < HID; k++) {
        wr[k] = w_hh[jc * HID + k];
        wz[k] = w_hh[(HID + jc) * HID + k];
        wn[k] = w_hh[(2 * HID + jc) * HID + k];
    }
    const float br = b_hh[jc];
    const float bz = b_hh[HID + jc];
    const float bn = b_hh[2 * HID + jc];
    const float hbv = hb[b * HID + jc];                 // hoisted for the epilogue

    float pr[PFD], pz[PFD], pn[PFD];
#pragma unroll
    for (int d = 0; d < PFD; d++) {
        pr[d] = gs[d * 32 + jc];
        pz[d] = gs[d * 32 + HID + jc];
        pn[d] = gs[d * 32 + 2 * HID + jc];
    }

    float h = 0.0f;
    float hs[HID];
#pragma unroll
    for (int k = 0; k < HID; k++) hs[k] = 0.0f;

    for (int tt = 0; tt < SEQ; tt += PFD) {
#pragma unroll
        for (int d = 0; d < PFD; d++) {
            const float ir = pr[d], iz = pz[d], in_ = pn[d];

            int tn = tt + d + PFD;
            if (tn >= SEQ) tn = SEQ - 1;
            const float* __restrict__ gp = gs + tn * 32;
            pr[d] = gp[jc];
            pz[d] = gp[HID + jc];
            pn[d] = gp[2 * HID + jc];

            // 2-accumulator dots: serial chain 5 FMAs instead of 10
            float ar0 = ir + br, ar1 = 0.0f;
            float az0 = iz + bz, az1 = 0.0f;
            float an0 = bn,      an1 = 0.0f;
#pragma unroll
            for (int k = 0; k < 5; k++) {
                ar0 = fmaf(wr[k], hs[k], ar0);
                az0 = fmaf(wz[k], hs[k], az0);
                an0 = fmaf(wn[k], hs[k], an0);
                ar1 = fmaf(wr[k + 5], hs[k + 5], ar1);
                az1 = fmaf(wz[k + 5], hs[k + 5], az1);
                an1 = fmaf(wn[k + 5], hs[k + 5], an1);
            }
            const float r = fsig(ar0 + ar1);
            const float z = fsig(az0 + az1);
            const float n = ftanh(fmaf(r, an0 + an1, in_));
            h = fmaf(z, h - n, n);                      // (1-z)*n + z*h

#pragma unroll
            for (int k = 0; k < HID; k++) hs[k] = rdlane(h, k);
        }
    }

    const float p = fmaf(w_lin[jc], h, w_lin[HID + jc] * hbv);
    float s = 0.0f;
#pragma unroll
    for (int k = 0; k < HID; k++) s += rdlane(p, k);
    if (j == 0) out[b] = s + b_lin[0];
}

// ---------------------------------------------------------------------------
extern "C" void kernel_launch(void* const* d_in, const int* in_sizes, int n_in,
                              void* d_out, int out_size, void* d_ws, size_t ws_size,
                              hipStream_t stream) {
    const float* x      = (const float*)d_in[0];
    const float* w_ih_f = (const float*)d_in[1];
    const float* w_hh_f = (const float*)d_in[2];
    const float* b_ih_f = (const float*)d_in[3];
    const float* b_hh_f = (const float*)d_in[4];
    const float* w_ih_b = (const float*)d_in[5];
    const float* w_hh_b = (const float*)d_in[6];   // unused: backward is one step, h0=0
    const float* b_ih_b = (const float*)d_in[7];
    const float* b_hh_b = (const float*)d_in[8];
    const float* w_lin  = (const float*)d_in[9];
    const float* b_lin  = (const float*)d_in[10];
    float* out = (float*)d_out;

    float* gi  = (float*)d_ws;                          // [ROWS][32] = 16.78 MB
    float* hb  = gi + (size_t)ROWS * 32;                // [BATCH][HID]
    short* wph = (short*)(hb + BATCH * HID);            // [32][320] bf16-hi
    short* wpl = wph + 32 * 320;                        // [32][320] bf16-lo
    (void)w_hh_b; (void)in_sizes; (void)n_in; (void)out_size; (void)ws_size;

    k_prep<<<(32 * 320 + 255) / 256, 256, 0, stream>>>(w_ih_f, wph, wpl);
    k_back<<<BATCH, 256, 0, stream>>>(x, w_ih_b, b_ih_b, b_hh_b, hb);
    k_gi  <<<ROWS / 64, 256, 0, stream>>>(x, wph, wpl, b_ih_f, gi);
    k_scan<<<BATCH, 256, 0, stream>>>(gi, w_hh_f, b_hh_f, hb, w_lin, b_lin, out);
}